// Round 7
// baseline (474.185 us; speedup 1.0000x reference)
//
#include <hip/hip_runtime.h>
#include <hip/hip_bf16.h>

#define IN_DIM 300
#define XDIM   320      // x row padded: 300 vals + bias-one at col 300 + zeros
#define MEM    1024
#define NTREE  16383

typedef _Float16 half8 __attribute__((ext_vector_type(8)));
typedef float    f32x4 __attribute__((ext_vector_type(4)));

__device__ __forceinline__ float sigf(float x) { return 1.0f / (1.0f + __expf(-x)); }
__device__ __forceinline__ float tanhfast(float x) { return 2.0f / (1.0f + __expf(-2.0f * x)) - 1.0f; }

#define GLOAD_LDS16(g, l) \
    __builtin_amdgcn_global_load_lds((const __attribute__((address_space(1))) void*)(g), \
                                     (__attribute__((address_space(3))) void*)(l), 16, 0, 0)

// ---------------------------------------------------------------------------
// Pack (one-time): Wiou16 = [Wih;Woh;Wuh] (3072x1024 fp16), Wfh16 (1024x1024),
// x16 (16384x320: [x | 1.0 | 0...]), Bx (4096x320: [Wgx | bgx+bgh | 0...],
// rows g=i,o,u,f).
// ---------------------------------------------------------------------------
__global__ void pack_kernel(
    const float* __restrict__ embs,
    const float* __restrict__ Wix, const float* __restrict__ bix,
    const float* __restrict__ Wih, const float* __restrict__ bih,
    const float* __restrict__ Wfx, const float* __restrict__ bfx,
    const float* __restrict__ Wfh, const float* __restrict__ bfh,
    const float* __restrict__ Wox, const float* __restrict__ box_,
    const float* __restrict__ Woh, const float* __restrict__ boh,
    const float* __restrict__ Wux, const float* __restrict__ bux,
    const float* __restrict__ Wuh, const float* __restrict__ buh,
    _Float16* __restrict__ Wiou16, _Float16* __restrict__ Wfh16,
    _Float16* __restrict__ x16, _Float16* __restrict__ Bx)
{
    long long idx = (long long)blockIdx.x * blockDim.x + threadIdx.x;
    const long long n_wiou = 3072LL * 1024;
    const long long n_wfh  = 1024LL * 1024;
    const long long n_x    = 16384LL * XDIM;
    const long long n_bx   = 4096LL * XDIM;
    if (idx < n_wiou) {
        int m = (int)(idx >> 10), k = (int)(idx & 1023);
        int g = m >> 10, mm = m & 1023;
        const float* W = (g == 0) ? Wih : (g == 1) ? Woh : Wuh;
        Wiou16[idx] = (_Float16)W[(long long)mm * MEM + k];
        return;
    }
    idx -= n_wiou;
    if (idx < n_wfh) {
        Wfh16[idx] = (_Float16)Wfh[idx];
        return;
    }
    idx -= n_wfh;
    if (idx < n_x) {
        int node = (int)(idx / XDIM), j = (int)(idx % XDIM);
        float v = 0.f;
        if (node < NTREE) {
            if (j < IN_DIM) v = embs[(long long)node * IN_DIM + j];
            else if (j == IN_DIM) v = 1.0f;
        }
        x16[idx] = (_Float16)v;
        return;
    }
    idx -= n_x;
    if (idx < n_bx) {
        int r = (int)(idx / XDIM), j = (int)(idx % XDIM);
        int g = r >> 10, mm = r & 1023;
        const float* Wx = (g == 0) ? Wix : (g == 1) ? Wox : (g == 2) ? Wux : Wfx;
        const float* b1 = (g == 0) ? bix : (g == 1) ? box_ : (g == 2) ? bux : bfx;
        const float* b2 = (g == 0) ? bih : (g == 1) ? boh : (g == 2) ? buh : bfh;
        float v = 0.f;
        if (j < IN_DIM) v = Wx[(long long)mm * IN_DIM + j];
        else if (j == IN_DIM) v = b1[mm] + b2[mm];
        Bx[idx] = (_Float16)v;
    }
}

// ---------------------------------------------------------------------------
// GEMM K-loop core (no C write): acc += A(BMxK) * B(BNxK)^T. Single-buffered
// m97 2-barrier structure (proven best at 2-phase). XOR-swizzled staging
// (rule 21: linear LDS dest + inverse-swizzled source + swizzled ds_read).
// ---------------------------------------------------------------------------
template<int BM, int BN, int BK>
__device__ __forceinline__ void gemm_core(
    const _Float16* __restrict__ A, int lda,
    const _Float16* __restrict__ B, int ldb, int K,
    _Float16* ldsA, _Float16* ldsB,
    f32x4 (&acc)[BM / 32][BN / 32])
{
    constexpr int FM = BM / 32, FN = BN / 32;
    constexpr int CPR = BK / 8, SWM = CPR - 1;
    constexpr int ACH = BM * BK / 2048, BCH = BN * BK / 2048;

    int tid = threadIdx.x, wave = tid >> 6, lane = tid & 63;
    int wr = (wave >> 1) * (BM / 2), wc = (wave & 1) * (BN / 2);
    int kq = (lane >> 4) * 8, rs = lane & 15;

    for (int k0 = 0; k0 < K; k0 += BK) {
#pragma unroll
        for (int j = 0; j < ACH; ++j) {
            int c = j * 256 + tid;
            int row = c / CPR;
            int s = (c ^ row) & SWM;
            GLOAD_LDS16(A + (long long)row * lda + k0 + s * 8,
                        &ldsA[(j * 256 + wave * 64) * 8]);
        }
#pragma unroll
        for (int j = 0; j < BCH; ++j) {
            int c = j * 256 + tid;
            int row = c / CPR;
            int s = (c ^ row) & SWM;
            GLOAD_LDS16(B + (long long)row * ldb + k0 + s * 8,
                        &ldsB[(j * 256 + wave * 64) * 8]);
        }
        __syncthreads();
#pragma unroll
        for (int kk = 0; kk < BK; kk += 32) {
            half8 a[FM], b[FN];
#pragma unroll
            for (int i = 0; i < FM; ++i) {
                int r = wr + i * 16 + rs;
                int s = ((kk + kq) >> 3) ^ (r & SWM);
                a[i] = *(const half8*)&ldsA[r * BK + s * 8];
            }
#pragma unroll
            for (int i = 0; i < FN; ++i) {
                int r = wc + i * 16 + rs;
                int s = ((kk + kq) >> 3) ^ (r & SWM);
                b[i] = *(const half8*)&ldsB[r * BK + s * 8];
            }
#pragma unroll
            for (int mi = 0; mi < FM; ++mi)
#pragma unroll
                for (int ni = 0; ni < FN; ++ni)
                    acc[mi][ni] = __builtin_amdgcn_mfma_f32_16x16x32_f16(a[mi], b[ni], acc[mi][ni], 0, 0, 0);
        }
        __syncthreads();
    }
}

// ---------------------------------------------------------------------------
// proj_fused: ONE launch = Xp GEMM (blocks 0..2047) + leaf GEMM+combine
// (blocks 2048..3071). Independent work, co-scheduled.
// Xp = x[0:8192] @ [Wix;Wox;Wux;Wfx]^T (+biases), 8192x4096, K=320.
// ---------------------------------------------------------------------------
__global__ __launch_bounds__(256) void proj_fused(
    const _Float16* __restrict__ x16, const _Float16* __restrict__ Bx,
    _Float16* __restrict__ Xp,
    _Float16* __restrict__ cleaf, _Float16* __restrict__ hleaf,
    _Float16* __restrict__ hsum)
{
    __shared__ __align__(16) _Float16 lds[448 * 32];   // 28 KB shared pool
    int tid = threadIdx.x, wave = tid >> 6, lane = tid & 63;
    int kq = (lane >> 4) * 8, rs = lane & 15;

    if (blockIdx.x < 2048) {
        int mb = blockIdx.x & 63, nb = blockIdx.x >> 6;   // 64 x 32 tiles
        f32x4 acc[4][4] = {};
        gemm_core<128, 128, 32>(x16 + (long long)mb * 128 * XDIM, XDIM,
                                Bx + (long long)nb * 128 * XDIM, XDIM, XDIM,
                                lds, lds + 4096, acc);
        int wr = (wave >> 1) * 64, wc = (wave & 1) * 64;
        int crb = wr + (lane >> 4) * 4, ccb = wc + rs;
#pragma unroll
        for (int mi = 0; mi < 4; ++mi)
#pragma unroll
            for (int i = 0; i < 4; ++i) {
                long long r = mb * 128 + crb + mi * 16 + i;
#pragma unroll
                for (int ni = 0; ni < 4; ++ni)
                    Xp[r * 4096 + nb * 128 + ccb + ni * 16] = (_Float16)acc[mi][ni][i];
            }
        return;
    }
    // ---- leaf part: 64 leaves x 128 cols, 3 gate groups, K=320
    {
        constexpr int BK = 32, CPR = 4, SWM = 3;
        _Float16* lA = lds;               //  64*32
        _Float16* lB = lds + 64 * 32;     // 384*32
        int bid = (int)blockIdx.x - 2048;
        int m0 = (bid & 127) * 64, c0 = (bid >> 7) * 128;
        int wr = (wave >> 1) * 32, wc = (wave & 1) * 64;
        const _Float16* A = x16 + (size_t)(8191 + m0) * XDIM;

        f32x4 acc[3][2][4] = {};
        for (int t = 0; t < 10; ++t) {     // K = 320
            int k0 = t * BK;
            {   // A: 256 chunks, 1/thread
                int c = tid, row = c / CPR, s = (c ^ row) & SWM;
                GLOAD_LDS16(A + (long long)row * XDIM + k0 + s * 8, &lA[(wave * 64) * 8]);
            }
#pragma unroll
            for (int j = 0; j < 6; ++j) {   // B: 1536 chunks (3 gate tiles x 128)
                int c = j * 256 + tid;
                int row = c / CPR, s = (c ^ row) & SWM;
                int g = row >> 7, rr = row & 127;
                GLOAD_LDS16(Bx + (long long)(g * 1024 + c0 + rr) * XDIM + k0 + s * 8,
                            &lB[(j * 256 + wave * 64) * 8]);
            }
            __syncthreads();
            half8 a[2], b[3][4];
#pragma unroll
            for (int mi = 0; mi < 2; ++mi) {
                int r = wr + mi * 16 + rs;
                int s = (kq >> 3) ^ (r & SWM);
                a[mi] = *(const half8*)&lA[r * BK + s * 8];
            }
#pragma unroll
            for (int g = 0; g < 3; ++g)
#pragma unroll
                for (int nj = 0; nj < 4; ++nj) {
                    int r = g * 128 + wc + nj * 16 + rs;
                    int s = (kq >> 3) ^ (r & SWM);
                    b[g][nj] = *(const half8*)&lB[r * BK + s * 8];
                }
#pragma unroll
            for (int g = 0; g < 3; ++g)
#pragma unroll
                for (int mi = 0; mi < 2; ++mi)
#pragma unroll
                    for (int nj = 0; nj < 4; ++nj)
                        acc[g][mi][nj] = __builtin_amdgcn_mfma_f32_16x16x32_f16(a[mi], b[g][nj], acc[g][mi][nj], 0, 0, 0);
            __syncthreads();
        }
        int lrb = wr + (lane >> 4) * 4;
#pragma unroll
        for (int mi = 0; mi < 2; ++mi)
#pragma unroll
            for (int nj = 0; nj < 4; ++nj) {
                int col = c0 + wc + nj * 16 + rs;
                float hpair = 0.f;
#pragma unroll
                for (int i = 0; i < 4; ++i) {
                    long long l = m0 + lrb + mi * 16 + i;
                    float cc = sigf(acc[0][mi][nj][i]) * tanhfast(acc[2][mi][nj][i]);
                    float hh = sigf(acc[1][mi][nj][i]) * tanhfast(cc);
                    cleaf[l * 1024 + col] = (_Float16)cc;
                    hleaf[l * 1024 + col] = (_Float16)hh;
                    if (i & 1) hsum[(l >> 1) * 1024 + col] = (_Float16)(hpair + hh);
                    else hpair = hh;
                }
            }
    }
}

// ---------------------------------------------------------------------------
// Big-level GEMM with activation epilogue: iou part writes ACTIVATED
// sig/sig/tanh(acc + Xp) (gate uniform per block = nb>>3); f part writes
// sig(acc + Xp_f(parent)). Combine then needs no Xp reads and no gate exps.
// ---------------------------------------------------------------------------
template<int BM1, int BM2, int BK>
__global__ __launch_bounds__(256) void gemm_level_act(
    const _Float16* __restrict__ Hsum, const _Float16* __restrict__ Hc,
    const _Float16* __restrict__ Wiou, const _Float16* __restrict__ Wf,
    const _Float16* __restrict__ Xp,
    _Float16* __restrict__ houact, _Float16* __restrict__ fact,
    int G1, int G2, int n)
{
    constexpr int BMX = (BM1 > BM2) ? BM1 : BM2;
    __shared__ __align__(16) _Float16 ldsA[BMX * BK];
    __shared__ __align__(16) _Float16 ldsB[128 * BK];
    int tid = threadIdx.x, wave = tid >> 6, lane = tid & 63;
    int bx = blockIdx.x;
    if (bx < G1 * 24) {
        int nb = bx / G1, mb = bx % G1;
        f32x4 acc[BM1 / 32][4] = {};
        gemm_core<BM1, 128, BK>(Hsum + (long long)mb * BM1 * 1024, 1024,
                                Wiou + (long long)nb * 128 * 1024, 1024, 1024,
                                ldsA, ldsB, acc);
        int gate = nb >> 3;
        int wr = (wave >> 1) * (BM1 / 2), wc = (wave & 1) * 64;
        int crb = wr + (lane >> 4) * 4, ccb = wc + (lane & 15);
#pragma unroll
        for (int mi = 0; mi < BM1 / 32; ++mi)
#pragma unroll
            for (int i = 0; i < 4; ++i) {
                long long row = mb * BM1 + crb + mi * 16 + i;
                long long node = (n - 1) + row;
#pragma unroll
                for (int ni = 0; ni < 4; ++ni) {
                    int col = nb * 128 + ccb + ni * 16;
                    float v = acc[mi][ni][i] + (float)Xp[node * 4096 + col];
                    float a = (gate == 2) ? tanhfast(v) : sigf(v);
                    houact[row * 3072 + col] = (_Float16)a;
                }
            }
    } else {
        int b2 = bx - G1 * 24;
        int nb = b2 / G2, mb = b2 % G2;
        f32x4 acc[BM2 / 32][4] = {};
        gemm_core<BM2, 128, BK>(Hc + (long long)mb * BM2 * 1024, 1024,
                                Wf + (long long)nb * 128 * 1024, 1024, 1024,
                                ldsA, ldsB, acc);
        int wr = (wave >> 1) * (BM2 / 2), wc = (wave & 1) * 64;
        int crb = wr + (lane >> 4) * 4, ccb = wc + (lane & 15);
#pragma unroll
        for (int mi = 0; mi < BM2 / 32; ++mi)
#pragma unroll
            for (int i = 0; i < 4; ++i) {
                long long row = mb * BM2 + crb + mi * 16 + i;     // child index
                long long node = (n - 1) + (row >> 1);            // parent node
#pragma unroll
                for (int ni = 0; ni < 4; ++ni) {
                    int col = nb * 128 + ccb + ni * 16;
                    float v = acc[mi][ni][i] + (float)Xp[node * 4096 + 3072 + col];
                    fact[row * 1024 + col] = (_Float16)sigf(v);
                }
            }
    }
}

// ---------------------------------------------------------------------------
// Big-level combine (activated inputs): c = i*u + f0*c0 + f1*c1,
// h = o*tanh(c). One transcendental per element.
// ---------------------------------------------------------------------------
template<bool C16>
__global__ void combine_act(
    const _Float16* __restrict__ houact, const _Float16* __restrict__ fact,
    const void* __restrict__ cprevp,
    float* __restrict__ cout, _Float16* __restrict__ hout, _Float16* __restrict__ hsum,
    int n)
{
    int idx = blockIdx.x * blockDim.x + threadIdx.x;
    int npairs = n >> 1;
    if (idx >= npairs * 128) return;
    int r = idx >> 7, m8 = (idx & 127) * 8;
    float hs[8];
#pragma unroll
    for (int j = 0; j < 8; ++j) hs[j] = 0.f;
    for (int t = 0; t < 2; ++t) {
        int p = 2 * r + t;
        half8 vi = *(const half8*)&houact[(long long)p * 3072 + m8];
        half8 vo = *(const half8*)&houact[(long long)p * 3072 + 1024 + m8];
        half8 vu = *(const half8*)&houact[(long long)p * 3072 + 2048 + m8];
        half8 f0 = *(const half8*)&fact[(long long)(2 * p) * 1024 + m8];
        half8 f1 = *(const half8*)&fact[(long long)(2 * p + 1) * 1024 + m8];
        float c0[8], c1[8];
        if (C16) {
            const _Float16* cp = (const _Float16*)cprevp;
            half8 a = *(const half8*)&cp[(long long)(2 * p) * 1024 + m8];
            half8 b = *(const half8*)&cp[(long long)(2 * p + 1) * 1024 + m8];
#pragma unroll
            for (int j = 0; j < 8; ++j) { c0[j] = (float)a[j]; c1[j] = (float)b[j]; }
        } else {
            const float* cp = (const float*)cprevp;
            f32x4 a0 = *(const f32x4*)&cp[(long long)(2 * p) * 1024 + m8];
            f32x4 a1 = *(const f32x4*)&cp[(long long)(2 * p) * 1024 + m8 + 4];
            f32x4 b0 = *(const f32x4*)&cp[(long long)(2 * p + 1) * 1024 + m8];
            f32x4 b1 = *(const f32x4*)&cp[(long long)(2 * p + 1) * 1024 + m8 + 4];
#pragma unroll
            for (int j = 0; j < 4; ++j) { c0[j] = a0[j]; c0[j + 4] = a1[j]; c1[j] = b0[j]; c1[j + 4] = b1[j]; }
        }
        float cw[8], hw[8];
#pragma unroll
        for (int j = 0; j < 8; ++j) {
            float c = (float)vi[j] * (float)vu[j]
                    + (float)f0[j] * c0[j] + (float)f1[j] * c1[j];
            float h = (float)vo[j] * tanhfast(c);
            cw[j] = c; hw[j] = h; hs[j] += h;
        }
        f32x4 v0 = {cw[0], cw[1], cw[2], cw[3]}, v1 = {cw[4], cw[5], cw[6], cw[7]};
        *(f32x4*)&cout[(long long)p * 1024 + m8] = v0;
        *(f32x4*)&cout[(long long)p * 1024 + m8 + 4] = v1;
        half8 hv;
#pragma unroll
        for (int j = 0; j < 8; ++j) hv[j] = (_Float16)hw[j];
        *(half8*)&hout[(long long)p * 1024 + m8] = hv;
    }
    half8 sv;
#pragma unroll
    for (int j = 0; j < 8; ++j) sv[j] = (_Float16)hs[j];
    *(half8*)&hsum[(long long)r * 1024 + m8] = sv;
}

// ---------------------------------------------------------------------------
// Split-K tail GEMM (levels n<=256): S=4 splits x (K=256 = 2 steps of BK=128).
// Serial K-chain per level: 2 steps instead of 8. Raw f32 partials; summed +
// activated in combine_tail. Stale A rows (row>=n) are read but discarded
// (MFMA rows are independent; buffers are allocated => safe).
// ---------------------------------------------------------------------------
__global__ __launch_bounds__(256) void tail_sk(
    const _Float16* __restrict__ Hs, const _Float16* __restrict__ Hc,
    const _Float16* __restrict__ Wiou, const _Float16* __restrict__ Wf,
    float* __restrict__ houp, float* __restrict__ fp,
    int n, int PTn, int PT2n)
{
    __shared__ __align__(16) _Float16 ldsA[64 * 128];
    __shared__ __align__(16) _Float16 ldsB[128 * 128];
    int tid = threadIdx.x, wave = tid >> 6, lane = tid & 63;
    int T = PTn * 24 + PT2n * 8;
    int s = blockIdx.x / T, r = blockIdx.x % T;
    int k0 = s * 256;
    f32x4 acc[2][4] = {};
    int wr = (wave >> 1) * 32, wc = (wave & 1) * 64;
    int crb = wr + (lane >> 4) * 4, ccb = wc + (lane & 15);
    if (r < PTn * 24) {
        int nb = r / PTn, mb = r % PTn;
        gemm_core<64, 128, 128>(Hs + (long long)mb * 64 * 1024 + k0, 1024,
                                Wiou + (long long)nb * 128 * 1024 + k0, 1024, 256,
                                ldsA, ldsB, acc);
#pragma unroll
        for (int mi = 0; mi < 2; ++mi)
#pragma unroll
            for (int i = 0; i < 4; ++i) {
                int row = mb * 64 + crb + mi * 16 + i;
                if (row >= n) continue;
#pragma unroll
                for (int ni = 0; ni < 4; ++ni)
                    houp[((long long)s * n + row) * 3072 + nb * 128 + ccb + ni * 16] = acc[mi][ni][i];
            }
    } else {
        int b2 = r - PTn * 24;
        int nb = b2 / PT2n, mb = b2 % PT2n;
        gemm_core<64, 128, 128>(Hc + (long long)mb * 64 * 1024 + k0, 1024,
                                Wf + (long long)nb * 128 * 1024 + k0, 1024, 256,
                                ldsA, ldsB, acc);
#pragma unroll
        for (int mi = 0; mi < 2; ++mi)
#pragma unroll
            for (int i = 0; i < 4; ++i) {
                int row = mb * 64 + crb + mi * 16 + i;
                if (row >= 2 * n) continue;
#pragma unroll
                for (int ni = 0; ni < 4; ++ni)
                    fp[((long long)s * 2 * n + row) * 1024 + nb * 128 + ccb + ni * 16] = acc[mi][ni][i];
            }
    }
}

// ---------------------------------------------------------------------------
// Tail combine: sum 4 split-K partials + Xp, activate, combine. cprev is f32
// for all tail levels. At lvl0 writes d_out = [c;h] f32.
// ---------------------------------------------------------------------------
__global__ void combine_tail(
    const float* __restrict__ houp, const float* __restrict__ fp,
    const float* __restrict__ cprev, const _Float16* __restrict__ Xp,
    float* __restrict__ cout, _Float16* __restrict__ hout, _Float16* __restrict__ hsum,
    int n, float* __restrict__ fin)
{
    int idx = blockIdx.x * blockDim.x + threadIdx.x;
    int npairs = (n > 1) ? (n >> 1) : 1;
    if (idx >= npairs * 128) return;
    int r = idx >> 7, m8 = (idx & 127) * 8;
    float hs[8];
#pragma unroll
    for (int j = 0; j < 8; ++j) hs[j] = 0.f;
    int pmax = (n > 1) ? 2 : 1;
    for (int t = 0; t < pmax; ++t) {
        int p = 2 * r + t;
        long long node = (n - 1) + p;
        float gi[8], go[8], gu[8], q0[8], q1[8];
        half8 xi = *(const half8*)&Xp[node * 4096 + m8];
        half8 xo = *(const half8*)&Xp[node * 4096 + 1024 + m8];
        half8 xu = *(const half8*)&Xp[node * 4096 + 2048 + m8];
        half8 xf = *(const half8*)&Xp[node * 4096 + 3072 + m8];
#pragma unroll
        for (int j = 0; j < 8; ++j) {
            gi[j] = (float)xi[j]; go[j] = (float)xo[j]; gu[j] = (float)xu[j];
            q0[j] = (float)xf[j]; q1[j] = (float)xf[j];
        }
#pragma unroll
        for (int s = 0; s < 4; ++s) {
            const float* hb = houp + ((long long)s * n + p) * 3072;
#pragma unroll
            for (int j = 0; j < 8; ++j) {
                gi[j] += hb[m8 + j];
                go[j] += hb[1024 + m8 + j];
                gu[j] += hb[2048 + m8 + j];
            }
            const float* fb0 = fp + ((long long)s * 2 * n + 2 * p) * 1024;
            const float* fb1 = fp + ((long long)s * 2 * n + 2 * p + 1) * 1024;
#pragma unroll
            for (int j = 0; j < 8; ++j) {
                q0[j] += fb0[m8 + j];
                q1[j] += fb1[m8 + j];
            }
        }
        float cw[8], hw[8];
#pragma unroll
        for (int j = 0; j < 8; ++j) {
            float i  = sigf(gi[j]);
            float o  = sigf(go[j]);
            float u  = tanhfast(gu[j]);
            float f0 = sigf(q0[j]);
            float f1 = sigf(q1[j]);
            float c = i * u + f0 * cprev[(long long)(2 * p) * 1024 + m8 + j]
                            + f1 * cprev[(long long)(2 * p + 1) * 1024 + m8 + j];
            float h = o * tanhfast(c);
            cw[j] = c; hw[j] = h; hs[j] += h;
        }
        if (fin) {
            f32x4 v0 = {cw[0], cw[1], cw[2], cw[3]}, v1 = {cw[4], cw[5], cw[6], cw[7]};
            f32x4 w0 = {hw[0], hw[1], hw[2], hw[3]}, w1 = {hw[4], hw[5], hw[6], hw[7]};
            *(f32x4*)&fin[m8] = v0;            *(f32x4*)&fin[m8 + 4] = v1;
            *(f32x4*)&fin[1024 + m8] = w0;     *(f32x4*)&fin[1024 + m8 + 4] = w1;
        } else {
            f32x4 v0 = {cw[0], cw[1], cw[2], cw[3]}, v1 = {cw[4], cw[5], cw[6], cw[7]};
            *(f32x4*)&cout[(long long)p * 1024 + m8] = v0;
            *(f32x4*)&cout[(long long)p * 1024 + m8 + 4] = v1;
            half8 hv;
#pragma unroll
            for (int j = 0; j < 8; ++j) hv[j] = (_Float16)hw[j];
            *(half8*)&hout[(long long)p * 1024 + m8] = hv;
        }
    }
    if (!fin) {
        half8 sv;
#pragma unroll
        for (int j = 0; j < 8; ++j) sv[j] = (_Float16)hs[j];
        *(half8*)&hsum[(long long)r * 1024 + m8] = sv;
    }
}

// ---------------------------------------------------------------------------
extern "C" void kernel_launch(void* const* d_in, const int* in_sizes, int n_in,
                              void* d_out, int out_size, void* d_ws, size_t ws_size,
                              hipStream_t stream)
{
    const float* embs = (const float*)d_in[0];
    const float* Wix = (const float*)d_in[1];  const float* bix = (const float*)d_in[2];
    const float* Wih = (const float*)d_in[3];  const float* bih = (const float*)d_in[4];
    const float* Wfx = (const float*)d_in[5];  const float* bfx = (const float*)d_in[6];
    const float* Wfh = (const float*)d_in[7];  const float* bfh = (const float*)d_in[8];
    const float* Wox = (const float*)d_in[9];  const float* box_ = (const float*)d_in[10];
    const float* Woh = (const float*)d_in[11]; const float* boh = (const float*)d_in[12];
    const float* Wux = (const float*)d_in[13]; const float* bux = (const float*)d_in[14];
    const float* Wuh = (const float*)d_in[15]; const float* buh = (const float*)d_in[16];

    char* p = (char*)d_ws;
    auto carve = [&](size_t bytes) -> char* {
        char* r = p; p += (bytes + 255) & ~(size_t)255; return r;
    };
    _Float16* Wiou16 = (_Float16*)carve((size_t)3072 * 1024 * 2);   //   6.3 MB
    _Float16* Wfh16  = (_Float16*)carve((size_t)1024 * 1024 * 2);   //   2.1 MB
    _Float16* Xp     = (_Float16*)carve((size_t)8192 * 4096 * 2);   //  67.1 MB (iou|f)
    _Float16* houact = (_Float16*)carve((size_t)4096 * 3072 * 2);   //  25.2 MB
    _Float16* fact   = (_Float16*)carve((size_t)8192 * 1024 * 2);   //  16.8 MB
    _Float16* H_A    = (_Float16*)carve((size_t)8192 * 1024 * 2);   //  16.8 MB
    _Float16* H_B    = (_Float16*)carve((size_t)4096 * 1024 * 2);   //   8.4 MB
    _Float16* HsumA  = (_Float16*)carve((size_t)4096 * 1024 * 2);   //   8.4 MB
    _Float16* HsumB  = (_Float16*)carve((size_t)4096 * 1024 * 2);   //   8.4 MB
    _Float16* Cleaf  = (_Float16*)carve((size_t)8192 * 1024 * 2);   //  16.8 MB
    float*    Cping  = (float*)carve((size_t)4096 * 1024 * 4);      //  16.8 MB
    float*    Cpong  = (float*)carve((size_t)2048 * 1024 * 4);      //   8.4 MB
    float*    houp4  = (float*)carve((size_t)4 * 256 * 3072 * 4);   //  12.6 MB
    float*    fp4    = (float*)carve((size_t)4 * 512 * 1024 * 4);   //   8.4 MB
    // total ~223 MB (<= r1's proven 225). Aliases (stream-ordered): x16/Bx
    // live in fact (13.1 MB <= 16.8), dead after proj_fused; fact first
    // written at lvl12 gemm_level_act.
    _Float16* x16 = fact;
    _Float16* Bx  = fact + (size_t)16384 * XDIM;

    {   // pack
        long long tot = 3072LL * 1024 + 1024LL * 1024 + 16384LL * XDIM + 4096LL * XDIM;
        pack_kernel<<<dim3((int)((tot + 255) / 256)), dim3(256), 0, stream>>>(
            embs, Wix, bix, Wih, bih, Wfx, bfx, Wfh, bfh,
            Wox, box_, Woh, boh, Wux, bux, Wuh, buh,
            Wiou16, Wfh16, x16, Bx);
    }

    // Xp GEMM + leaf level in ONE launch
    proj_fused<<<dim3(3072), dim3(256), 0, stream>>>(
        x16, Bx, Xp, Cleaf, H_A, HsumA);

    const void* cprev = Cleaf;
    float* cbufs[2] = {Cping, Cpong};
    _Float16* hsums[2] = {HsumA, HsumB};
    int ci = 0, si = 0;
    _Float16* hcur = H_A;
    _Float16* hnext = H_B;

    // Big levels: lvl 12..9 (n = 4096..512)
    for (int lvl = 12; lvl >= 9; --lvl) {
        int n = 1 << lvl;
        int G1 = n / 128, G2 = 2 * n / 128;
        if (n >= 1024)
            gemm_level_act<128, 128, 32><<<dim3(G1 * 24 + G2 * 8), dim3(256), 0, stream>>>(
                hsums[si], hcur, Wiou16, Wfh16, Xp, houact, fact, G1, G2, n);
        else
            gemm_level_act<128, 128, 128><<<dim3(G1 * 24 + G2 * 8), dim3(256), 0, stream>>>(
                hsums[si], hcur, Wiou16, Wfh16, Xp, houact, fact, G1, G2, n);
        int blocks = ((n >> 1) * 128 + 255) / 256;
        if (lvl == 12)
            combine_act<true><<<dim3(blocks), dim3(256), 0, stream>>>(
                houact, fact, cprev, cbufs[ci], hnext, hsums[si ^ 1], n);
        else
            combine_act<false><<<dim3(blocks), dim3(256), 0, stream>>>(
                houact, fact, cprev, cbufs[ci], hnext, hsums[si ^ 1], n);
        cprev = cbufs[ci];
        ci ^= 1; si ^= 1;
        _Float16* tmp = hcur; hcur = hnext; hnext = tmp;
    }

    // Tail: lvl 8..0 (n = 256..1), split-K (S=4) + combine per level
    for (int lvl = 8; lvl >= 0; --lvl) {
        int n = 1 << lvl;
        int PTn = (n + 63) / 64, PT2n = (2 * n + 63) / 64;
        int T = PTn * 24 + PT2n * 8;
        tail_sk<<<dim3(T * 4), dim3(256), 0, stream>>>(
            hsums[si], hcur, Wiou16, Wfh16, houp4, fp4, n, PTn, PT2n);
        int npairs = (n > 1) ? (n >> 1) : 1;
        int blocks = (npairs * 128 + 255) / 256;
        combine_tail<<<dim3(blocks), dim3(256), 0, stream>>>(
            houp4, fp4, (const float*)cprev, Xp,
            cbufs[ci], hnext, hsums[si ^ 1], n,
            (lvl == 0) ? (float*)d_out : nullptr);
        cprev = cbufs[ci];
        ci ^= 1; si ^= 1;
        _Float16* tmp = hcur; hcur = hnext; hnext = tmp;
    }
}